// Round 1
// baseline (21750.392 us; speedup 1.0000x reference)
//
#include <hip/hip_runtime.h>

// R1: persistent cooperative-style LSTM, bf16 MFMA, hand-rolled grid barrier.
// Layout facts used (learn_hip-verified): mfma_f32_16x16x32_bf16 C/D:
// col=lane&15, row=(lane>>4)*4+reg. A/B k-slots use a consistent bijection
// k = (lane>>4)*8 + e for both operands (contraction-dim relabel is safe),
// with W stored transposed (Wt[n][k]) so both frags are contiguous 16B loads.

typedef unsigned short u16;
typedef unsigned int u32;
typedef __attribute__((ext_vector_type(8))) short bf16x8;
typedef __attribute__((ext_vector_type(4))) float f32x4;

#define NBLK 64
#define SEQ 512
#define BATCH 64
#define HID 1024
#define KDIM 2048
#define NGATES 4096

__device__ __forceinline__ u16 f2bf(float f) {
  u32 u = __builtin_bit_cast(u32, f);
  u += 0x7FFFu + ((u >> 16) & 1u);   // RNE
  return (u16)(u >> 16);
}

// ---------- prep: W [2048][4096] f32 -> Wt [4096][2048] bf16 (transposed); zero barrier ----------
__global__ void prep_w(const float* __restrict__ W, u16* __restrict__ Wt,
                       u32* __restrict__ bar) {
  __shared__ float tile[64][65];
  const int kb = blockIdx.x * 64;   // k tile (row of W)
  const int nb = blockIdx.y * 64;   // n tile (col of W)
  const int tx = threadIdx.x & 63;
  const int ty = threadIdx.x >> 6;
  for (int r = ty; r < 64; r += 4)
    tile[r][tx] = W[(size_t)(kb + r) * NGATES + nb + tx];
  __syncthreads();
  for (int r = ty; r < 64; r += 4)
    Wt[(size_t)(nb + r) * KDIM + kb + tx] = f2bf(tile[tx][r]);
  if (blockIdx.x == 0 && blockIdx.y == 0 && threadIdx.x < 128)
    bar[threadIdx.x] = 0;
}

// ---------- prep: x f32 -> bf16 ----------
__global__ void prep_x(const float* __restrict__ x, u16* __restrict__ xb) {
  const size_t n4 = (size_t)SEQ * BATCH * HID / 4;
  size_t i = (size_t)blockIdx.x * blockDim.x + threadIdx.x;
  const size_t stride = (size_t)gridDim.x * blockDim.x;
  for (; i < n4; i += stride) {
    const float4 v = *(const float4*)(x + i * 4);
    u32 lo = (u32)f2bf(v.x) | ((u32)f2bf(v.y) << 16);
    u32 hi = (u32)f2bf(v.z) | ((u32)f2bf(v.w) << 16);
    *(uint2*)(xb + i * 4) = make_uint2(lo, hi);
  }
}

// ---------- grid barrier: per-block flags + block-0 aggregator (monotone generations) ----------
__device__ __forceinline__ void gridbar(u32* bar, u32 s) {
  __syncthreads();
  const int tid = threadIdx.x;
  if (tid == 0) {
    __threadfence();  // publish this block's stores (agent scope: wb past XCD L2)
    __hip_atomic_store(bar + blockIdx.x, s, __ATOMIC_RELEASE, __HIP_MEMORY_SCOPE_AGENT);
  }
  if (blockIdx.x == 0) {
    if (tid < NBLK) {
      while (__hip_atomic_load(bar + tid, __ATOMIC_ACQUIRE, __HIP_MEMORY_SCOPE_AGENT) < s)
        __builtin_amdgcn_s_sleep(1);
    }
    __syncthreads();
    if (tid == 0)
      __hip_atomic_store(bar + NBLK, s, __ATOMIC_RELEASE, __HIP_MEMORY_SCOPE_AGENT);
  } else {
    if (tid == 0) {
      while (__hip_atomic_load(bar + NBLK, __ATOMIC_ACQUIRE, __HIP_MEMORY_SCOPE_AGENT) < s)
        __builtin_amdgcn_s_sleep(1);
    }
  }
  if (tid == 0) __threadfence();  // invalidate stale L1/L2 before re-reading h
  __syncthreads();
}

// ---------- persistent LSTM ----------
// 64 blocks x 512 thr (8 waves = 4 M-tiles x 2 K-halves). Block owns 16 cols/gate.
__global__ __launch_bounds__(512) void lstm_pers(
    const u16* __restrict__ xb,      // [512][64][1024] bf16
    const float* __restrict__ bias,  // [4096]
    const float* __restrict__ h0,    // [1024]
    const float* __restrict__ c0,    // [1024]
    const u16* __restrict__ Wt,      // [4096][2048] bf16
    u16* __restrict__ hbuf,          // [2][64][1024] bf16
    float* __restrict__ out,         // [2][64][1024] f32 (h then c)
    u32* __restrict__ bar)
{
  __shared__ float red[4][4][256];   // [m-tile][gate][reg*64+lane]
  const int tid = threadIdx.x;
  const int lane = tid & 63;
  const int wave = tid >> 6;
  const int wm = wave & 3;           // M tile (16 batch rows)
  const int wh = wave >> 2;          // K half: 0 = h part, 1 = x part
  const int bid = blockIdx.x;
  const int col16 = lane & 15;
  const int kg = lane >> 4;
  const int n0 = bid * 16;

  // init h broadcast (h0 -> both? only buf0 needed)
  for (int i = bid * 512 + tid; i < BATCH * HID; i += NBLK * 512)
    hbuf[i] = f2bf(h0[i & (HID - 1)]);
  u32 s = 0;
  gridbar(bar, ++s);

  const int colg = n0 + col16;             // column within each gate
  const float bf_ = bias[colg];
  const float bi_ = bias[HID + colg];
  const float bg_ = bias[2 * HID + colg];
  const float bo_ = bias[3 * HID + colg];

  const size_t GSTRIDE = (size_t)HID * KDIM;
  const u16* bp0 = Wt + (size_t)colg * KDIM + (size_t)wh * HID + kg * 8;
  const u16* bp1 = bp0 + GSTRIDE;
  const u16* bp2 = bp0 + 2 * GSTRIDE;
  const u16* bp3 = bp0 + 3 * GSTRIDE;

  const size_t aoff = (size_t)(wm * 16 + col16) * HID + kg * 8;

  // c state lives in registers: lane owns rows wm*16+kg*4+{0..3}, col colg (wh==0 waves)
  float creg[4];
  #pragma unroll
  for (int r = 0; r < 4; ++r) creg[r] = c0[colg];

  for (int t = 0; t < SEQ; ++t) {
    const u16* abase = wh ? (xb + (size_t)t * (BATCH * HID) + aoff)
                          : (hbuf + (size_t)(t & 1) * (BATCH * HID) + aoff);
    f32x4 accf = {0.f, 0.f, 0.f, 0.f}, acci = accf, accg = accf, acco = accf;
    #pragma unroll 4
    for (int kk = 0; kk < 32; ++kk) {
      bf16x8 av = *(const bf16x8*)(abase + kk * 32);
      bf16x8 b0 = *(const bf16x8*)(bp0 + kk * 32);
      bf16x8 b1 = *(const bf16x8*)(bp1 + kk * 32);
      bf16x8 b2 = *(const bf16x8*)(bp2 + kk * 32);
      bf16x8 b3 = *(const bf16x8*)(bp3 + kk * 32);
      accf = __builtin_amdgcn_mfma_f32_16x16x32_bf16(av, b0, accf, 0, 0, 0);
      acci = __builtin_amdgcn_mfma_f32_16x16x32_bf16(av, b1, acci, 0, 0, 0);
      accg = __builtin_amdgcn_mfma_f32_16x16x32_bf16(av, b2, accg, 0, 0, 0);
      acco = __builtin_amdgcn_mfma_f32_16x16x32_bf16(av, b3, acco, 0, 0, 0);
    }
    if (wh == 1) {
      #pragma unroll
      for (int r = 0; r < 4; ++r) {
        red[wm][0][r * 64 + lane] = accf[r];
        red[wm][1][r * 64 + lane] = acci[r];
        red[wm][2][r * 64 + lane] = accg[r];
        red[wm][3][r * 64 + lane] = acco[r];
      }
    }
    __syncthreads();
    if (wh == 0) {
      u16* hw = hbuf + (size_t)((t + 1) & 1) * (BATCH * HID);
      #pragma unroll
      for (int r = 0; r < 4; ++r) {
        const int row = wm * 16 + kg * 4 + r;        // C/D: row=(lane>>4)*4+reg
        const size_t idx = (size_t)row * HID + colg; // col = lane&15 (+gate base)
        float vf = accf[r] + red[wm][0][r * 64 + lane] + bf_;
        float vi = acci[r] + red[wm][1][r * 64 + lane] + bi_;
        float vg = accg[r] + red[wm][2][r * 64 + lane] + bg_;
        float vo = acco[r] + red[wm][3][r * 64 + lane] + bo_;
        float ft = 1.f / (1.f + __expf(-vf));
        float it = 1.f / (1.f + __expf(-vi));
        float eg = __expf(2.f * vg);
        float gt = 1.f - 2.f / (eg + 1.f);           // tanh
        float ot = 1.f / (1.f + __expf(-vo));
        float cn = ft * creg[r] + it * gt;
        float ec = __expf(2.f * cn);
        float th = 1.f - 2.f / (ec + 1.f);           // tanh
        float hn = ot * th;
        creg[r] = cn;
        hw[idx] = f2bf(hn);
        if (t == SEQ - 1) { out[idx] = hn; out[BATCH * HID + idx] = cn; }
      }
    }
    gridbar(bar, ++s);
  }
}

extern "C" void kernel_launch(void* const* d_in, const int* in_sizes, int n_in,
                              void* d_out, int out_size, void* d_ws, size_t ws_size,
                              hipStream_t stream) {
  const float* x    = (const float*)d_in[0];  // [512][64][1024]
  const float* W    = (const float*)d_in[1];  // [2048][4096]
  const float* bias = (const float*)d_in[2];  // [4096]
  const float* h0   = (const float*)d_in[3];  // [1024]
  const float* c0   = (const float*)d_in[4];  // [1024]
  float* out = (float*)d_out;                 // [2][64][1024]

  char* w = (char*)d_ws;
  u16* Wt   = (u16*)w;                                   // 16 MB
  u16* xb   = (u16*)(w + ((size_t)16 << 20));            // 64 MB
  u16* hbuf = (u16*)(w + ((size_t)80 << 20));            // 256 KB
  u32* bar  = (u32*)(w + ((size_t)80 << 20) + (512 << 10));
  const size_t need = ((size_t)80 << 20) + (512 << 10) + 4096;
  if (ws_size < need) return;  // fail visibly rather than corrupt

  hipLaunchKernelGGL(prep_w, dim3(32, 64), dim3(256), 0, stream, W, Wt, bar);
  hipLaunchKernelGGL(prep_x, dim3(4096), dim3(256), 0, stream, x, xb);
  hipLaunchKernelGGL(lstm_pers, dim3(NBLK), dim3(512), 0, stream,
                     xb, bias, h0, c0, Wt, hbuf, out, bar);
}

// Round 2
// 17865.425 us; speedup vs baseline: 1.2175x; 1.2175x over previous
//
#include <hip/hip_runtime.h>

// R2: persistent LSTM, W resident (Wh in VGPRs, Wx in LDS) so the per-step
// agent-fence L2 invalidation only costs the broadcast-shared h/x refills.
// x-partial MFMA for step t+1 runs between arrive and wait (hides barrier).

typedef unsigned short u16;
typedef unsigned int u32;
typedef __attribute__((ext_vector_type(8))) short bf16x8;
typedef __attribute__((ext_vector_type(4))) float f32x4;

#define NBLK 64
#define SEQ 512
#define BATCH 64
#define HID 1024
#define KDIM 2048
#define NGATES 4096
#define GB_STRIDE 68   // 68 % 32 banks: kg groups land 2-way (free) on ds ops
#define WX_BYTES 131072
#define SMEM_BYTES (WX_BYTES + 64 * GB_STRIDE * 4)

__device__ __forceinline__ u16 f2bf(float f) {
  u32 u = __builtin_bit_cast(u32, f);
  u += 0x7FFFu + ((u >> 16) & 1u);   // RNE
  return (u16)(u >> 16);
}

// ---------- prep: W [2048][4096] f32 -> Wt [4096][2048] bf16 (transposed); zero flags ----------
__global__ void prep_w(const float* __restrict__ W, u16* __restrict__ Wt,
                       u32* __restrict__ bar) {
  __shared__ float tile[64][65];
  const int kb = blockIdx.x * 64;
  const int nb = blockIdx.y * 64;
  const int tx = threadIdx.x & 63;
  const int ty = threadIdx.x >> 6;
  for (int r = ty; r < 64; r += 4)
    tile[r][tx] = W[(size_t)(kb + r) * NGATES + nb + tx];
  __syncthreads();
  for (int r = ty; r < 64; r += 4)
    Wt[(size_t)(nb + r) * KDIM + kb + tx] = f2bf(tile[tx][r]);
  if (blockIdx.x == 0 && blockIdx.y == 0 && threadIdx.x < 128)
    bar[threadIdx.x] = 0;
}

// ---------- prep: x f32 -> bf16 ----------
__global__ void prep_x(const float* __restrict__ x, u16* __restrict__ xb) {
  const size_t n4 = (size_t)SEQ * BATCH * HID / 4;
  size_t i = (size_t)blockIdx.x * blockDim.x + threadIdx.x;
  const size_t stride = (size_t)gridDim.x * blockDim.x;
  for (; i < n4; i += stride) {
    const float4 v = *(const float4*)(x + i * 4);
    u32 lo = (u32)f2bf(v.x) | ((u32)f2bf(v.y) << 16);
    u32 hi = (u32)f2bf(v.z) | ((u32)f2bf(v.w) << 16);
    *(uint2*)(xb + i * 4) = make_uint2(lo, hi);
  }
}

// ---------- persistent LSTM ----------
// 64 blocks x 512 thr. waves: kq = wave>>1 (K quarter of 256), nh = wave&1
// (gate pair: nh*2+{0,1}). Block owns cols bid*16..+15 of each gate.
__global__ __launch_bounds__(512, 2) void lstm_pers(
    const u16* __restrict__ xb,      // [512][64][1024] bf16
    const float* __restrict__ bias,  // [4096]
    const float* __restrict__ h0,    // [1024]
    const float* __restrict__ c0,    // [1024]
    const u16* __restrict__ Wt,      // [4096][2048] bf16
    u16* __restrict__ hbuf,          // [2][64][1024] bf16
    float* __restrict__ out,         // [2][64][1024] f32 (h then c)
    u32* __restrict__ bar)
{
  extern __shared__ char smem[];
  u16* wx = (u16*)smem;                     // [wave][frag16][lane64][8] bf16, 128 KB
  float* gb = (float*)(smem + WX_BYTES);    // [64][GB_STRIDE] f32 gate sums

  const int tid = threadIdx.x;
  const int lane = tid & 63;
  const int wave = tid >> 6;
  const int nh = wave & 1;
  const int kq = wave >> 1;
  const int col16 = lane & 15;
  const int kg = lane >> 4;
  const int bid = blockIdx.x;

  // ---- one-time: Wh -> regs, Wx -> LDS (fragment-order, stride-16B = conflict-free) ----
  bf16x8 wh[8][2];
  u16* wxw = wx + (size_t)wave * (16 * 64 * 8) + (size_t)lane * 8;
  #pragma unroll
  for (int kt = 0; kt < 8; ++kt) {
    #pragma unroll
    for (int nt = 0; nt < 2; ++nt) {
      const int g = nh * 2 + nt;
      const u16* wrow = Wt + (size_t)(g * HID + bid * 16 + col16) * KDIM
                           + kq * 256 + kt * 32 + kg * 8;
      wh[kt][nt] = *(const bf16x8*)(wrow);                                  // h half
      *(bf16x8*)(wxw + (size_t)(kt * 2 + nt) * (64 * 8)) =
          *(const bf16x8*)(wrow + HID);                                     // x half
    }
  }
  const float bv0 = bias[(nh * 2 + 0) * HID + bid * 16 + col16];
  const float bv1 = bias[(nh * 2 + 1) * HID + bid * 16 + col16];

  // ---- per-thread output cells (row r0 and r0+32, col colg); c in regs ----
  const int r0 = tid >> 4;                 // 0..31
  const int colg = bid * 16 + (tid & 15);
  float cst0 = c0[colg], cst1 = cst0;
  {
    u16 h0b = f2bf(h0[colg]);
    hbuf[(size_t)r0 * HID + colg] = h0b;
    hbuf[(size_t)(r0 + 32) * HID + colg] = h0b;
  }
  __syncthreads();
  if (tid == 0) {
    __threadfence();
    __hip_atomic_store(bar + bid, 1u, __ATOMIC_RELEASE, __HIP_MEMORY_SCOPE_AGENT);
  }

  f32x4 acc[4][2];
  const size_t aoff = (size_t)col16 * HID + kq * 256 + kg * 8;

  // x-partial for step t -> acc (C-in chain; zeroes acc first). Overlaps barrier wait.
  auto xphase = [&](int t) {
    #pragma unroll
    for (int mt = 0; mt < 4; ++mt) {
      acc[mt][0] = (f32x4){0.f, 0.f, 0.f, 0.f};
      acc[mt][1] = (f32x4){0.f, 0.f, 0.f, 0.f};
    }
    const u16* xbase = xb + (size_t)t * (BATCH * HID) + aoff;
    #pragma unroll
    for (int mt = 0; mt < 4; ++mt) {
      bf16x8 a[8];
      #pragma unroll
      for (int kt = 0; kt < 8; ++kt)
        a[kt] = *(const bf16x8*)(xbase + (size_t)mt * 16 * HID + kt * 32);
      #pragma unroll
      for (int kt = 0; kt < 8; ++kt) {
        bf16x8 w0 = *(const bf16x8*)(wxw + (size_t)(kt * 2 + 0) * (64 * 8));
        bf16x8 w1 = *(const bf16x8*)(wxw + (size_t)(kt * 2 + 1) * (64 * 8));
        acc[mt][0] = __builtin_amdgcn_mfma_f32_16x16x32_bf16(a[kt], w0, acc[mt][0], 0, 0, 0);
        acc[mt][1] = __builtin_amdgcn_mfma_f32_16x16x32_bf16(a[kt], w1, acc[mt][1], 0, 0, 0);
      }
    }
  };

  xphase(0);

  for (int t = 0; t < SEQ; ++t) {
    const u32 gen = (u32)t + 1;
    // ---- wait for h_t from all blocks ----
    if (tid < NBLK) {
      while (__hip_atomic_load(bar + tid, __ATOMIC_ACQUIRE, __HIP_MEMORY_SCOPE_AGENT) < gen)
        __builtin_amdgcn_s_sleep(1);
    }
    __syncthreads();
    if (tid == 0) __threadfence();   // invalidate L1/L2 before reading fresh h
    __syncthreads();

    // ---- h_t * Wh accumulated on top of the stashed x-partial ----
    const u16* hbase = hbuf + (size_t)(t & 1) * (BATCH * HID) + aoff;
    #pragma unroll
    for (int mt = 0; mt < 4; ++mt) {
      bf16x8 a[8];
      #pragma unroll
      for (int kt = 0; kt < 8; ++kt)
        a[kt] = *(const bf16x8*)(hbase + (size_t)mt * 16 * HID + kt * 32);
      #pragma unroll
      for (int kt = 0; kt < 8; ++kt) {
        acc[mt][0] = __builtin_amdgcn_mfma_f32_16x16x32_bf16(a[kt], wh[kt][0], acc[mt][0], 0, 0, 0);
        acc[mt][1] = __builtin_amdgcn_mfma_f32_16x16x32_bf16(a[kt], wh[kt][1], acc[mt][1], 0, 0, 0);
      }
    }

    // ---- K-reduction across kq waves in LDS ----
    if (kq == 0) {
      #pragma unroll
      for (int mt = 0; mt < 4; ++mt)
        #pragma unroll
        for (int nt = 0; nt < 2; ++nt) {
          const float bv = nt ? bv1 : bv0;
          #pragma unroll
          for (int r = 0; r < 4; ++r)
            gb[(mt * 16 + kg * 4 + r) * GB_STRIDE + (nh * 2 + nt) * 16 + col16] =
                acc[mt][nt][r] + bv;
        }
    }
    __syncthreads();
    if (kq != 0) {
      #pragma unroll
      for (int mt = 0; mt < 4; ++mt)
        #pragma unroll
        for (int nt = 0; nt < 2; ++nt)
          #pragma unroll
          for (int r = 0; r < 4; ++r)
            atomicAdd(&gb[(mt * 16 + kg * 4 + r) * GB_STRIDE + (nh * 2 + nt) * 16 + col16],
                      acc[mt][nt][r]);
    }
    __syncthreads();

    // ---- gates -> nonlinearity -> c,h update (2 cells/thread) ----
    u16* hw = hbuf + (size_t)((t + 1) & 1) * (BATCH * HID);
    const int cl = tid & 15;
    #pragma unroll
    for (int cc = 0; cc < 2; ++cc) {
      const int row = r0 + cc * 32;
      const float vf = gb[row * GB_STRIDE + cl];
      const float vi = gb[row * GB_STRIDE + 16 + cl];
      const float vg = gb[row * GB_STRIDE + 32 + cl];
      const float vo = gb[row * GB_STRIDE + 48 + cl];
      const float ft = 1.f / (1.f + __expf(-vf));
      const float it = 1.f / (1.f + __expf(-vi));
      const float eg = __expf(2.f * vg);
      const float gt = 1.f - 2.f / (eg + 1.f);     // tanh
      const float ot = 1.f / (1.f + __expf(-vo));
      const float cold = cc ? cst1 : cst0;
      const float cn = ft * cold + it * gt;
      const float ec = __expf(2.f * cn);
      const float th = 1.f - 2.f / (ec + 1.f);     // tanh
      const float hn = ot * th;
      if (cc) cst1 = cn; else cst0 = cn;
      hw[(size_t)row * HID + colg] = f2bf(hn);
      if (t == SEQ - 1) {
        out[(size_t)row * HID + colg] = hn;
        out[(size_t)BATCH * HID + (size_t)row * HID + colg] = cn;
      }
    }
    __syncthreads();   // all h stores drained (vmcnt) before fence+flag

    if (t < SEQ - 1) {
      if (tid == 0) {
        __threadfence();   // write back h to LLC
        __hip_atomic_store(bar + bid, gen + 1, __ATOMIC_RELEASE, __HIP_MEMORY_SCOPE_AGENT);
      }
      xphase(t + 1);       // overlap barrier wait with x-partial for t+1
    }
  }
}

extern "C" void kernel_launch(void* const* d_in, const int* in_sizes, int n_in,
                              void* d_out, int out_size, void* d_ws, size_t ws_size,
                              hipStream_t stream) {
  const float* x    = (const float*)d_in[0];  // [512][64][1024]
  const float* W    = (const float*)d_in[1];  // [2048][4096]
  const float* bias = (const float*)d_in[2];  // [4096]
  const float* h0   = (const float*)d_in[3];  // [1024]
  const float* c0   = (const float*)d_in[4];  // [1024]
  float* out = (float*)d_out;                 // [2][64][1024]

  char* w = (char*)d_ws;
  u16* Wt   = (u16*)w;                                   // 16 MB
  u16* xb   = (u16*)(w + ((size_t)16 << 20));            // 64 MB
  u16* hbuf = (u16*)(w + ((size_t)80 << 20));            // 256 KB
  u32* bar  = (u32*)(w + ((size_t)80 << 20) + (512 << 10));
  const size_t need = ((size_t)80 << 20) + (512 << 10) + 4096;
  if (ws_size < need) return;

  (void)hipFuncSetAttribute((const void*)lstm_pers,
                            hipFuncAttributeMaxDynamicSharedMemorySize, SMEM_BYTES);

  hipLaunchKernelGGL(prep_w, dim3(32, 64), dim3(256), 0, stream, W, Wt, bar);
  hipLaunchKernelGGL(prep_x, dim3(4096), dim3(256), 0, stream, x, xb);
  hipLaunchKernelGGL(lstm_pers, dim3(NBLK), dim3(512), SMEM_BYTES, stream,
                     xb, bias, h0, c0, Wt, hbuf, out, bar);
}

// Round 3
// 17162.141 us; speedup vs baseline: 1.2673x; 1.0410x over previous
//
#include <hip/hip_runtime.h>

// R3: same as R2 (W resident: Wh in VGPRs, Wx in LDS; x-partial overlaps the
// barrier wait) but the grid barrier no longer flash-invalidates L2 per poll:
// RELAXED polling + ONE acquire fence after the wait; release via the flag
// store only (no seq_cst threadfence). Mechanism: agent-scope ACQUIRE loads
// emit buffer_inv each iteration -> continuous XCD-L2 flash-invalidate ->
// every sibling load becomes an LLC round trip (R2: 34 GB/s, 35 us/step).

typedef unsigned short u16;
typedef unsigned int u32;
typedef __attribute__((ext_vector_type(8))) short bf16x8;
typedef __attribute__((ext_vector_type(4))) float f32x4;

#define NBLK 64
#define SEQ 512
#define BATCH 64
#define HID 1024
#define KDIM 2048
#define NGATES 4096
#define GB_STRIDE 68
#define WX_BYTES 131072
#define SMEM_BYTES (WX_BYTES + 64 * GB_STRIDE * 4)

__device__ __forceinline__ u16 f2bf(float f) {
  u32 u = __builtin_bit_cast(u32, f);
  u += 0x7FFFu + ((u >> 16) & 1u);   // RNE
  return (u16)(u >> 16);
}

// ---------- prep: W [2048][4096] f32 -> Wt [4096][2048] bf16 (transposed); zero flags ----------
__global__ void prep_w(const float* __restrict__ W, u16* __restrict__ Wt,
                       u32* __restrict__ bar) {
  __shared__ float tile[64][65];
  const int kb = blockIdx.x * 64;
  const int nb = blockIdx.y * 64;
  const int tx = threadIdx.x & 63;
  const int ty = threadIdx.x >> 6;
  for (int r = ty; r < 64; r += 4)
    tile[r][tx] = W[(size_t)(kb + r) * NGATES + nb + tx];
  __syncthreads();
  for (int r = ty; r < 64; r += 4)
    Wt[(size_t)(nb + r) * KDIM + kb + tx] = f2bf(tile[tx][r]);
  if (blockIdx.x == 0 && blockIdx.y == 0 && threadIdx.x < 128)
    bar[threadIdx.x] = 0;
}

// ---------- prep: x f32 -> bf16 ----------
__global__ void prep_x(const float* __restrict__ x, u16* __restrict__ xb) {
  const size_t n4 = (size_t)SEQ * BATCH * HID / 4;
  size_t i = (size_t)blockIdx.x * blockDim.x + threadIdx.x;
  const size_t stride = (size_t)gridDim.x * blockDim.x;
  for (; i < n4; i += stride) {
    const float4 v = *(const float4*)(x + i * 4);
    u32 lo = (u32)f2bf(v.x) | ((u32)f2bf(v.y) << 16);
    u32 hi = (u32)f2bf(v.z) | ((u32)f2bf(v.w) << 16);
    *(uint2*)(xb + i * 4) = make_uint2(lo, hi);
  }
}

// ---------- persistent LSTM ----------
__global__ __launch_bounds__(512, 2) void lstm_pers(
    const u16* __restrict__ xb,      // [512][64][1024] bf16
    const float* __restrict__ bias,  // [4096]
    const float* __restrict__ h0,    // [1024]
    const float* __restrict__ c0,    // [1024]
    const u16* __restrict__ Wt,      // [4096][2048] bf16
    u16* __restrict__ hbuf,          // [2][64][1024] bf16
    float* __restrict__ out,         // [2][64][1024] f32 (h then c)
    u32* __restrict__ bar)
{
  extern __shared__ char smem[];
  u16* wx = (u16*)smem;                     // [wave][frag16][lane64][8] bf16, 128 KB
  float* gb = (float*)(smem + WX_BYTES);    // [64][GB_STRIDE] f32 gate sums

  const int tid = threadIdx.x;
  const int lane = tid & 63;
  const int wave = tid >> 6;
  const int nh = wave & 1;
  const int kq = wave >> 1;
  const int col16 = lane & 15;
  const int kg = lane >> 4;
  const int bid = blockIdx.x;

  // ---- one-time: Wh -> regs, Wx -> LDS (fragment-order, stride-16B = conflict-free) ----
  bf16x8 wh[8][2];
  u16* wxw = wx + (size_t)wave * (16 * 64 * 8) + (size_t)lane * 8;
  #pragma unroll
  for (int kt = 0; kt < 8; ++kt) {
    #pragma unroll
    for (int nt = 0; nt < 2; ++nt) {
      const int g = nh * 2 + nt;
      const u16* wrow = Wt + (size_t)(g * HID + bid * 16 + col16) * KDIM
                           + kq * 256 + kt * 32 + kg * 8;
      wh[kt][nt] = *(const bf16x8*)(wrow);                                  // h half
      *(bf16x8*)(wxw + (size_t)(kt * 2 + nt) * (64 * 8)) =
          *(const bf16x8*)(wrow + HID);                                     // x half
    }
  }
  const float bv0 = bias[(nh * 2 + 0) * HID + bid * 16 + col16];
  const float bv1 = bias[(nh * 2 + 1) * HID + bid * 16 + col16];

  // ---- per-thread output cells (row r0 and r0+32, col colg); c in regs ----
  const int r0 = tid >> 4;                 // 0..31
  const int colg = bid * 16 + (tid & 15);
  float cst0 = c0[colg], cst1 = cst0;
  {
    u16 h0b = f2bf(h0[colg]);
    hbuf[(size_t)r0 * HID + colg] = h0b;
    hbuf[(size_t)(r0 + 32) * HID + colg] = h0b;
  }
  __syncthreads();   // drains each wave's vmcnt -> h0 stores are in L2
  if (tid == 0)
    __hip_atomic_store(bar + bid, 1u, __ATOMIC_RELEASE, __HIP_MEMORY_SCOPE_AGENT);

  f32x4 acc[4][2];
  const size_t aoff = (size_t)col16 * HID + kq * 256 + kg * 8;

  // x-partial for step t -> acc (zeroes acc, C-in chain). Overlaps barrier wait.
  auto xphase = [&](int t) {
    #pragma unroll
    for (int mt = 0; mt < 4; ++mt) {
      acc[mt][0] = (f32x4){0.f, 0.f, 0.f, 0.f};
      acc[mt][1] = (f32x4){0.f, 0.f, 0.f, 0.f};
    }
    const u16* xbase = xb + (size_t)t * (BATCH * HID) + aoff;
    #pragma unroll
    for (int mt = 0; mt < 4; ++mt) {
      bf16x8 a[8];
      #pragma unroll
      for (int kt = 0; kt < 8; ++kt)
        a[kt] = *(const bf16x8*)(xbase + (size_t)mt * 16 * HID + kt * 32);
      #pragma unroll
      for (int kt = 0; kt < 8; ++kt) {
        bf16x8 w0 = *(const bf16x8*)(wxw + (size_t)(kt * 2 + 0) * (64 * 8));
        bf16x8 w1 = *(const bf16x8*)(wxw + (size_t)(kt * 2 + 1) * (64 * 8));
        acc[mt][0] = __builtin_amdgcn_mfma_f32_16x16x32_bf16(a[kt], w0, acc[mt][0], 0, 0, 0);
        acc[mt][1] = __builtin_amdgcn_mfma_f32_16x16x32_bf16(a[kt], w1, acc[mt][1], 0, 0, 0);
      }
    }
  };

  xphase(0);

  for (int t = 0; t < SEQ; ++t) {
    const u32 gen = (u32)t + 1;
    // ---- wait for h_t from all blocks: RELAXED poll (no per-iter buffer_inv) ----
    if (tid < NBLK) {
      while (__hip_atomic_load(bar + tid, __ATOMIC_RELAXED, __HIP_MEMORY_SCOPE_AGENT) < gen)
        __builtin_amdgcn_s_sleep(1);
    }
    __syncthreads();
    if (tid == 0)
      __builtin_amdgcn_fence(__ATOMIC_ACQUIRE, "agent");  // ONE inv per step
    __syncthreads();

    // ---- h_t * Wh accumulated on top of the stashed x-partial ----
    const u16* hbase = hbuf + (size_t)(t & 1) * (BATCH * HID) + aoff;
    #pragma unroll
    for (int mt = 0; mt < 4; ++mt) {
      bf16x8 a[8];
      #pragma unroll
      for (int kt = 0; kt < 8; ++kt)
        a[kt] = *(const bf16x8*)(hbase + (size_t)mt * 16 * HID + kt * 32);
      #pragma unroll
      for (int kt = 0; kt < 8; ++kt) {
        acc[mt][0] = __builtin_amdgcn_mfma_f32_16x16x32_bf16(a[kt], wh[kt][0], acc[mt][0], 0, 0, 0);
        acc[mt][1] = __builtin_amdgcn_mfma_f32_16x16x32_bf16(a[kt], wh[kt][1], acc[mt][1], 0, 0, 0);
      }
    }

    // ---- K-reduction across kq waves in LDS ----
    if (kq == 0) {
      #pragma unroll
      for (int mt = 0; mt < 4; ++mt)
        #pragma unroll
        for (int nt = 0; nt < 2; ++nt) {
          const float bv = nt ? bv1 : bv0;
          #pragma unroll
          for (int r = 0; r < 4; ++r)
            gb[(mt * 16 + kg * 4 + r) * GB_STRIDE + (nh * 2 + nt) * 16 + col16] =
                acc[mt][nt][r] + bv;
        }
    }
    __syncthreads();
    if (kq != 0) {
      #pragma unroll
      for (int mt = 0; mt < 4; ++mt)
        #pragma unroll
        for (int nt = 0; nt < 2; ++nt)
          #pragma unroll
          for (int r = 0; r < 4; ++r)
            atomicAdd(&gb[(mt * 16 + kg * 4 + r) * GB_STRIDE + (nh * 2 + nt) * 16 + col16],
                      acc[mt][nt][r]);
    }
    __syncthreads();

    // ---- gates -> nonlinearity -> c,h update (2 cells/thread) ----
    u16* hw = hbuf + (size_t)((t + 1) & 1) * (BATCH * HID);
    const int cl = tid & 15;
    #pragma unroll
    for (int cc = 0; cc < 2; ++cc) {
      const int row = r0 + cc * 32;
      const float vf = gb[row * GB_STRIDE + cl];
      const float vi = gb[row * GB_STRIDE + 16 + cl];
      const float vg = gb[row * GB_STRIDE + 32 + cl];
      const float vo = gb[row * GB_STRIDE + 48 + cl];
      const float ft = 1.f / (1.f + __expf(-vf));
      const float it = 1.f / (1.f + __expf(-vi));
      const float eg = __expf(2.f * vg);
      const float gt = 1.f - 2.f / (eg + 1.f);     // tanh
      const float ot = 1.f / (1.f + __expf(-vo));
      const float cold = cc ? cst1 : cst0;
      const float cn = ft * cold + it * gt;
      const float ec = __expf(2.f * cn);
      const float th = 1.f - 2.f / (ec + 1.f);     // tanh
      const float hn = ot * th;
      if (cc) cst1 = cn; else cst0 = cn;
      hw[(size_t)row * HID + colg] = f2bf(hn);
      if (t == SEQ - 1) {
        out[(size_t)row * HID + colg] = hn;
        out[(size_t)BATCH * HID + (size_t)row * HID + colg] = cn;
      }
    }
    __syncthreads();   // all waves' h stores drained (vmcnt) into L2

    if (t < SEQ - 1) {
      if (tid == 0)  // release store: waitcnt + wbl2 + flag (no inv)
        __hip_atomic_store(bar + bid, gen + 1, __ATOMIC_RELEASE, __HIP_MEMORY_SCOPE_AGENT);
      xphase(t + 1);   // overlap barrier wait with x-partial for t+1
    }
  }
}

extern "C" void kernel_launch(void* const* d_in, const int* in_sizes, int n_in,
                              void* d_out, int out_size, void* d_ws, size_t ws_size,
                              hipStream_t stream) {
  const float* x    = (const float*)d_in[0];  // [512][64][1024]
  const float* W    = (const float*)d_in[1];  // [2048][4096]
  const float* bias = (const float*)d_in[2];  // [4096]
  const float* h0   = (const float*)d_in[3];  // [1024]
  const float* c0   = (const float*)d_in[4];  // [1024]
  float* out = (float*)d_out;                 // [2][64][1024]

  char* w = (char*)d_ws;
  u16* Wt   = (u16*)w;                                   // 16 MB
  u16* xb   = (u16*)(w + ((size_t)16 << 20));            // 64 MB
  u16* hbuf = (u16*)(w + ((size_t)80 << 20));            // 256 KB
  u32* bar  = (u32*)(w + ((size_t)80 << 20) + (512 << 10));
  const size_t need = ((size_t)80 << 20) + (512 << 10) + 4096;
  if (ws_size < need) return;

  (void)hipFuncSetAttribute((const void*)lstm_pers,
                            hipFuncAttributeMaxDynamicSharedMemorySize, SMEM_BYTES);

  hipLaunchKernelGGL(prep_w, dim3(32, 64), dim3(256), 0, stream, W, Wt, bar);
  hipLaunchKernelGGL(prep_x, dim3(4096), dim3(256), 0, stream, x, xb);
  hipLaunchKernelGGL(lstm_pers, dim3(NBLK), dim3(512), SMEM_BYTES, stream,
                     xb, bias, h0, c0, Wt, hbuf, out, bar);
}

// Round 4
// 15925.635 us; speedup vs baseline: 1.3657x; 1.0776x over previous
//
#include <hip/hip_runtime.h>

// R4: persistent LSTM; ALL cross-block state (h, barrier flags) moves through
// explicit LLC-coherent accesses (sc0 sc1 = bypass L1/L2, perform at Infinity
// Cache). Zero cache-maintenance ops (no buffer_inv / buffer_wbl2) in the
// step loop -> L2 keeps x/W lines forever; h exchange is ~2 pipelined LLC
// round trips. R1-R3 all burned 33-42 us/step on agent-scope fence semantics.

typedef unsigned short u16;
typedef unsigned int u32;
typedef __attribute__((ext_vector_type(8))) short bf16x8;
typedef __attribute__((ext_vector_type(4))) float f32x4;

#define NBLK 64
#define SEQ 512
#define BATCH 64
#define HID 1024
#define KDIM 2048
#define NGATES 4096
#define GB_STRIDE 68
#define WX_BYTES 131072
#define SMEM_BYTES (WX_BYTES + 64 * GB_STRIDE * 4)

__device__ __forceinline__ u16 f2bf(float f) {
  u32 u = __builtin_bit_cast(u32, f);
  u += 0x7FFFu + ((u >> 16) & 1u);   // RNE
  return (u16)(u >> 16);
}

// ---- LLC-coherent primitives (gfx940+ sc0 sc1 = device-coherent, no L1/L2 alloc) ----
__device__ __forceinline__ void llc_store_u16(u16* p, u16 v) {
  asm volatile("global_store_short %0, %1, off sc0 sc1" :: "v"(p), "v"((u32)v) : "memory");
}
__device__ __forceinline__ void llc_store_u32(u32* p, u32 v) {
  asm volatile("global_store_dword %0, %1, off sc0 sc1" :: "v"(p), "v"(v) : "memory");
}
__device__ __forceinline__ u32 llc_load_u32(const u32* p) {
  u32 r;
  asm volatile("global_load_dword %0, %1, off sc0 sc1\n\ts_waitcnt vmcnt(0)"
               : "=v"(r) : "v"(p) : "memory");
  return r;
}
// 8 x 16B LLC loads off one base address (offsets kt*64B), fire-and-forget.
#define LLC_LOAD8(dst, ap)                                                   \
  asm volatile("global_load_dwordx4 %0, %8, off sc0 sc1\n\t"                 \
               "global_load_dwordx4 %1, %8, off offset:64 sc0 sc1\n\t"       \
               "global_load_dwordx4 %2, %8, off offset:128 sc0 sc1\n\t"      \
               "global_load_dwordx4 %3, %8, off offset:192 sc0 sc1\n\t"      \
               "global_load_dwordx4 %4, %8, off offset:256 sc0 sc1\n\t"      \
               "global_load_dwordx4 %5, %8, off offset:320 sc0 sc1\n\t"      \
               "global_load_dwordx4 %6, %8, off offset:384 sc0 sc1\n\t"      \
               "global_load_dwordx4 %7, %8, off offset:448 sc0 sc1"          \
               : "=&v"(dst[0]), "=&v"(dst[1]), "=&v"(dst[2]), "=&v"(dst[3]), \
                 "=&v"(dst[4]), "=&v"(dst[5]), "=&v"(dst[6]), "=&v"(dst[7])  \
               : "v"(ap))

// ---------- prep: W [2048][4096] f32 -> Wt [4096][2048] bf16 (transposed); zero flags ----------
__global__ void prep_w(const float* __restrict__ W, u16* __restrict__ Wt,
                       u32* __restrict__ bar) {
  __shared__ float tile[64][65];
  const int kb = blockIdx.x * 64;
  const int nb = blockIdx.y * 64;
  const int tx = threadIdx.x & 63;
  const int ty = threadIdx.x >> 6;
  for (int r = ty; r < 64; r += 4)
    tile[r][tx] = W[(size_t)(kb + r) * NGATES + nb + tx];
  __syncthreads();
  for (int r = ty; r < 64; r += 4)
    Wt[(size_t)(nb + r) * KDIM + kb + tx] = f2bf(tile[tx][r]);
  if (blockIdx.x == 0 && blockIdx.y == 0 && threadIdx.x < 128)
    bar[threadIdx.x] = 0;
}

// ---------- prep: x f32 -> bf16 ----------
__global__ void prep_x(const float* __restrict__ x, u16* __restrict__ xb) {
  const size_t n4 = (size_t)SEQ * BATCH * HID / 4;
  size_t i = (size_t)blockIdx.x * blockDim.x + threadIdx.x;
  const size_t stride = (size_t)gridDim.x * blockDim.x;
  for (; i < n4; i += stride) {
    const float4 v = *(const float4*)(x + i * 4);
    u32 lo = (u32)f2bf(v.x) | ((u32)f2bf(v.y) << 16);
    u32 hi = (u32)f2bf(v.z) | ((u32)f2bf(v.w) << 16);
    *(uint2*)(xb + i * 4) = make_uint2(lo, hi);
  }
}

// ---------- persistent LSTM ----------
__global__ __launch_bounds__(512) void lstm_pers(
    const u16* __restrict__ xb,      // [512][64][1024] bf16
    const float* __restrict__ bias,  // [4096]
    const float* __restrict__ h0,    // [1024]
    const float* __restrict__ c0,    // [1024]
    const u16* __restrict__ Wt,      // [4096][2048] bf16
    u16* __restrict__ hbuf,          // [2][64][1024] bf16  (LLC-coherent traffic)
    float* __restrict__ out,         // [2][64][1024] f32 (h then c)
    u32* __restrict__ bar)
{
  extern __shared__ char smem[];
  u16* wx = (u16*)smem;                     // [wave][frag16][lane64][8] bf16, 128 KB
  float* gb = (float*)(smem + WX_BYTES);    // [64][GB_STRIDE] f32 gate sums

  const int tid = threadIdx.x;
  const int lane = tid & 63;
  const int wave = tid >> 6;
  const int nh = wave & 1;
  const int kq = wave >> 1;
  const int col16 = lane & 15;
  const int kg = lane >> 4;
  const int bid = blockIdx.x;

  // ---- one-time: Wh -> regs, Wx -> LDS (fragment-order, stride-16B = conflict-free) ----
  bf16x8 wh[8][2];
  u16* wxw = wx + (size_t)wave * (16 * 64 * 8) + (size_t)lane * 8;
  #pragma unroll
  for (int kt = 0; kt < 8; ++kt) {
    #pragma unroll
    for (int nt = 0; nt < 2; ++nt) {
      const int g = nh * 2 + nt;
      const u16* wrow = Wt + (size_t)(g * HID + bid * 16 + col16) * KDIM
                           + kq * 256 + kt * 32 + kg * 8;
      wh[kt][nt] = *(const bf16x8*)(wrow);                                  // h half
      *(bf16x8*)(wxw + (size_t)(kt * 2 + nt) * (64 * 8)) =
          *(const bf16x8*)(wrow + HID);                                     // x half
    }
  }
  const float bv0 = bias[(nh * 2 + 0) * HID + bid * 16 + col16];
  const float bv1 = bias[(nh * 2 + 1) * HID + bid * 16 + col16];

  // ---- per-thread output cells (rows r0, r0+32; col colg); c in regs ----
  const int r0 = tid >> 4;
  const int colg = bid * 16 + (tid & 15);
  float cst0 = c0[colg], cst1 = cst0;
  {
    u16 h0b = f2bf(h0[colg]);
    llc_store_u16(hbuf + (size_t)r0 * HID + colg, h0b);
    llc_store_u16(hbuf + (size_t)(r0 + 32) * HID + colg, h0b);
  }
  __syncthreads();   // vmcnt(0) per wave -> h0 write-through acked at LLC
  if (tid == 0) llc_store_u32(bar + bid, 1u);

  f32x4 acc[4][2];
  const size_t aoff = (size_t)col16 * HID + kq * 256 + kg * 8;

  // x-partial for step t -> acc (zeroes acc, C-in chain). Overlaps barrier wait.
  auto xphase = [&](int t) {
    #pragma unroll
    for (int mt = 0; mt < 4; ++mt) {
      acc[mt][0] = (f32x4){0.f, 0.f, 0.f, 0.f};
      acc[mt][1] = (f32x4){0.f, 0.f, 0.f, 0.f};
    }
    const u16* xbase = xb + (size_t)t * (BATCH * HID) + aoff;
    #pragma unroll
    for (int mt = 0; mt < 4; ++mt) {
      bf16x8 a[8];
      #pragma unroll
      for (int kt = 0; kt < 8; ++kt)
        a[kt] = *(const bf16x8*)(xbase + (size_t)mt * 16 * HID + kt * 32);
      #pragma unroll
      for (int kt = 0; kt < 8; ++kt) {
        bf16x8 w0 = *(const bf16x8*)(wxw + (size_t)(kt * 2 + 0) * (64 * 8));
        bf16x8 w1 = *(const bf16x8*)(wxw + (size_t)(kt * 2 + 1) * (64 * 8));
        acc[mt][0] = __builtin_amdgcn_mfma_f32_16x16x32_bf16(a[kt], w0, acc[mt][0], 0, 0, 0);
        acc[mt][1] = __builtin_amdgcn_mfma_f32_16x16x32_bf16(a[kt], w1, acc[mt][1], 0, 0, 0);
      }
    }
  };

  xphase(0);

  for (int t = 0; t < SEQ; ++t) {
    const u32 gen = (u32)t + 1;
    // ---- wait for h_t: LLC-fresh poll, no cache maintenance ----
    if (tid < NBLK) {
      for (;;) {
        u32 fl = llc_load_u32(bar + tid);
        if (fl >= gen) break;
        __builtin_amdgcn_s_sleep(1);
      }
    }
    __syncthreads();

    // ---- h_t * Wh on top of stashed x-partial; h via pipelined LLC loads ----
    const u16* hbase = hbuf + (size_t)(t & 1) * (BATCH * HID) + aoff;
    {
      bf16x8 ha[8], hb2[8];
      asm volatile("s_waitcnt vmcnt(0)" ::: "memory");  // exact baseline for counted waits
      LLC_LOAD8(ha, hbase);
      #pragma unroll
      for (int mt = 0; mt < 4; ++mt) {
        if (mt < 3) {
          const u16* hn = hbase + (size_t)(mt + 1) * 16 * HID;
          if (mt & 1) { LLC_LOAD8(ha, hn); } else { LLC_LOAD8(hb2, hn); }
          asm volatile("s_waitcnt vmcnt(8)" ::: "memory");
        } else {
          asm volatile("s_waitcnt vmcnt(0)" ::: "memory");
        }
        __builtin_amdgcn_sched_barrier(0);
        #pragma unroll
        for (int kt = 0; kt < 8; ++kt) {
          bf16x8 av = (mt & 1) ? hb2[kt] : ha[kt];
          acc[mt][0] = __builtin_amdgcn_mfma_f32_16x16x32_bf16(av, wh[kt][0], acc[mt][0], 0, 0, 0);
          acc[mt][1] = __builtin_amdgcn_mfma_f32_16x16x32_bf16(av, wh[kt][1], acc[mt][1], 0, 0, 0);
        }
      }
    }

    // ---- K-reduction across kq waves in LDS ----
    if (kq == 0) {
      #pragma unroll
      for (int mt = 0; mt < 4; ++mt)
        #pragma unroll
        for (int nt = 0; nt < 2; ++nt) {
          const float bv = nt ? bv1 : bv0;
          #pragma unroll
          for (int r = 0; r < 4; ++r)
            gb[(mt * 16 + kg * 4 + r) * GB_STRIDE + (nh * 2 + nt) * 16 + col16] =
                acc[mt][nt][r] + bv;
        }
    }
    __syncthreads();
    if (kq != 0) {
      #pragma unroll
      for (int mt = 0; mt < 4; ++mt)
        #pragma unroll
        for (int nt = 0; nt < 2; ++nt)
          #pragma unroll
          for (int r = 0; r < 4; ++r)
            atomicAdd(&gb[(mt * 16 + kg * 4 + r) * GB_STRIDE + (nh * 2 + nt) * 16 + col16],
                      acc[mt][nt][r]);
    }
    __syncthreads();

    // ---- gates -> nonlinearity -> c,h update (2 cells/thread) ----
    u16* hw = hbuf + (size_t)((t + 1) & 1) * (BATCH * HID);
    const int cl = tid & 15;
    #pragma unroll
    for (int cc = 0; cc < 2; ++cc) {
      const int row = r0 + cc * 32;
      const float vf = gb[row * GB_STRIDE + cl];
      const float vi = gb[row * GB_STRIDE + 16 + cl];
      const float vg = gb[row * GB_STRIDE + 32 + cl];
      const float vo = gb[row * GB_STRIDE + 48 + cl];
      const float ft = 1.f / (1.f + __expf(-vf));
      const float it = 1.f / (1.f + __expf(-vi));
      const float eg = __expf(2.f * vg);
      const float gt = 1.f - 2.f / (eg + 1.f);     // tanh
      const float ot = 1.f / (1.f + __expf(-vo));
      const float cold = cc ? cst1 : cst0;
      const float cn = ft * cold + it * gt;
      const float ec = __expf(2.f * cn);
      const float th = 1.f - 2.f / (ec + 1.f);     // tanh
      const float hn = ot * th;
      if (cc) cst1 = cn; else cst0 = cn;
      llc_store_u16(hw + (size_t)row * HID + colg, f2bf(hn));
      if (t == SEQ - 1) {
        out[(size_t)row * HID + colg] = hn;
        out[(size_t)BATCH * HID + (size_t)row * HID + colg] = cn;
      }
    }
    __syncthreads();   // every wave's write-through h stores acked at LLC

    if (t < SEQ - 1) {
      if (tid == 0) llc_store_u32(bar + bid, gen + 1);  // release (h already at LLC)
      xphase(t + 1);   // overlap other blocks' progress with x-partial for t+1
    }
  }
}

extern "C" void kernel_launch(void* const* d_in, const int* in_sizes, int n_in,
                              void* d_out, int out_size, void* d_ws, size_t ws_size,
                              hipStream_t stream) {
  const float* x    = (const float*)d_in[0];  // [512][64][1024]
  const float* W    = (const float*)d_in[1];  // [2048][4096]
  const float* bias = (const float*)d_in[2];  // [4096]
  const float* h0   = (const float*)d_in[3];  // [1024]
  const float* c0   = (const float*)d_in[4];  // [1024]
  float* out = (float*)d_out;                 // [2][64][1024]

  char* w = (char*)d_ws;
  u16* Wt   = (u16*)w;                                   // 16 MB
  u16* xb   = (u16*)(w + ((size_t)16 << 20));            // 64 MB
  u16* hbuf = (u16*)(w + ((size_t)80 << 20));            // 256 KB
  u32* bar  = (u32*)(w + ((size_t)80 << 20) + (512 << 10));
  const size_t need = ((size_t)80 << 20) + (512 << 10) + 4096;
  if (ws_size < need) return;

  (void)hipFuncSetAttribute((const void*)lstm_pers,
                            hipFuncAttributeMaxDynamicSharedMemorySize, SMEM_BYTES);

  hipLaunchKernelGGL(prep_w, dim3(32, 64), dim3(256), 0, stream, W, Wt, bar);
  hipLaunchKernelGGL(prep_x, dim3(4096), dim3(256), 0, stream, x, xb);
  hipLaunchKernelGGL(lstm_pers, dim3(NBLK), dim3(512), SMEM_BYTES, stream,
                     xb, bias, h0, c0, Wt, hbuf, out, bar);
}

// Round 6
// 13412.527 us; speedup vs baseline: 1.6216x; 1.1874x over previous
//
#include <hip/hip_runtime.h>

// R6: split the problem. gates_x = x@Wx has NO recurrence -> precompute all
// 512 steps in a parallel prepass (256 CUs, ~0.2ms). The persistent sequential
// kernel per step does ONLY: poll -> h@Wh (W in VGPRs, h via LLC sc0sc1
// pipeline) -> LDS reduce -> nonlinearity -> release. Plus clock-warming
// filler blocks (DVFS: 1%-util kernels sit at low clock, inflating every
// latency term). Host-side fallback to the proven R4 kernel if ws < 337MB.

typedef unsigned short u16;
typedef unsigned int u32;
typedef __attribute__((ext_vector_type(8))) short bf16x8;
typedef __attribute__((ext_vector_type(4))) float f32x4;

#define NBLK 64          // worker blocks
#define NBLK_TOTAL 256   // workers + clock-warming fillers
#define SEQ 512
#define BATCH 64
#define HID 1024
#define KDIM 2048
#define NGATES 4096
#define GB_STRIDE 68
#define WX_BYTES 131072
#define SMEM_FB (WX_BYTES + 64 * GB_STRIDE * 4)   // fallback kernel LDS
#define XS_STRIDE 1032                             // 1024 + 8 pad (bank spread)
#define SMEM_PP (64 * XS_STRIDE * 2)               // prepass LDS: 132096 B
#define DONE_FLAG 96

__device__ __forceinline__ u16 f2bf(float f) {
  u32 u = __builtin_bit_cast(u32, f);
  u += 0x7FFFu + ((u >> 16) & 1u);   // RNE
  return (u16)(u >> 16);
}
__device__ __forceinline__ float bf2f(u32 v) {
  return __builtin_bit_cast(float, v << 16);
}

// ---- LLC-coherent primitives (sc0 sc1 = device-coherent, bypass L1/L2) ----
__device__ __forceinline__ void llc_store_u16(u16* p, u16 v) {
  asm volatile("global_store_short %0, %1, off sc0 sc1" :: "v"(p), "v"((u32)v) : "memory");
}
__device__ __forceinline__ void llc_store_u32(u32* p, u32 v) {
  asm volatile("global_store_dword %0, %1, off sc0 sc1" :: "v"(p), "v"(v) : "memory");
}
__device__ __forceinline__ u32 llc_load_u32(const u32* p) {
  u32 r;
  asm volatile("global_load_dword %0, %1, off sc0 sc1\n\ts_waitcnt vmcnt(0)"
               : "=v"(r) : "v"(p) : "memory");
  return r;
}
#define LLC_LOAD8(dst, ap)                                                   \
  asm volatile("global_load_dwordx4 %0, %8, off sc0 sc1\n\t"                 \
               "global_load_dwordx4 %1, %8, off offset:64 sc0 sc1\n\t"       \
               "global_load_dwordx4 %2, %8, off offset:128 sc0 sc1\n\t"      \
               "global_load_dwordx4 %3, %8, off offset:192 sc0 sc1\n\t"      \
               "global_load_dwordx4 %4, %8, off offset:256 sc0 sc1\n\t"      \
               "global_load_dwordx4 %5, %8, off offset:320 sc0 sc1\n\t"      \
               "global_load_dwordx4 %6, %8, off offset:384 sc0 sc1\n\t"      \
               "global_load_dwordx4 %7, %8, off offset:448 sc0 sc1"          \
               : "=&v"(dst[0]), "=&v"(dst[1]), "=&v"(dst[2]), "=&v"(dst[3]), \
                 "=&v"(dst[4]), "=&v"(dst[5]), "=&v"(dst[6]), "=&v"(dst[7])  \
               : "v"(ap))

// ---------- prep: W [2048][4096] f32 -> Wt [4096][2048] bf16 (transposed); zero flags ----------
__global__ void prep_w(const float* __restrict__ W, u16* __restrict__ Wt,
                       u32* __restrict__ bar) {
  __shared__ float tile[64][65];
  const int kb = blockIdx.x * 64;
  const int nb = blockIdx.y * 64;
  const int tx = threadIdx.x & 63;
  const int ty = threadIdx.x >> 6;
  for (int r = ty; r < 64; r += 4)
    tile[r][tx] = W[(size_t)(kb + r) * NGATES + nb + tx];
  __syncthreads();
  for (int r = ty; r < 64; r += 4)
    Wt[(size_t)(nb + r) * KDIM + kb + tx] = f2bf(tile[tx][r]);
  if (blockIdx.x == 0 && blockIdx.y == 0 && threadIdx.x < 128)
    bar[threadIdx.x] = 0;
}

// ---------- prep: x f32 -> bf16 ----------
__global__ void prep_x(const float* __restrict__ x, u16* __restrict__ xb) {
  const size_t n4 = (size_t)SEQ * BATCH * HID / 4;
  size_t i = (size_t)blockIdx.x * blockDim.x + threadIdx.x;
  const size_t stride = (size_t)gridDim.x * blockDim.x;
  for (; i < n4; i += stride) {
    const float4 v = *(const float4*)(x + i * 4);
    u32 lo = (u32)f2bf(v.x) | ((u32)f2bf(v.y) << 16);
    u32 hi = (u32)f2bf(v.z) | ((u32)f2bf(v.w) << 16);
    *(uint2*)(xb + i * 4) = make_uint2(lo, hi);
  }
}

// ---------- prepass: gxF[bid][t][g][c16][row64] bf16 = (x_t @ Wx) fragment-layout ----------
// 256 blocks x 512 thr; block p does steps 2p, 2p+1. Wave w: gate g=w>>1,
// within-gate 512-col strip (w&1); nt picks the 16-col tile -> seq-block bid16.
__global__ __launch_bounds__(512) void prepass_gx(
    const u16* __restrict__ xb, const u16* __restrict__ Wt, u16* __restrict__ gxF)
{
  extern __shared__ u16 xs[];     // [64][XS_STRIDE]
  const int tid = threadIdx.x;
  const int lane = tid & 63;
  const int wv = tid >> 6;
  const int col16 = lane & 15;
  const int kg = lane >> 4;
  const int t0 = blockIdx.x * 2;

  for (int tp = 0; tp < 2; ++tp) {
    const int t = t0 + tp;
    if (tp) __syncthreads();                 // protect LDS overwrite
    const u16* xsrc = xb + (size_t)t * (BATCH * HID);
    #pragma unroll
    for (int it = 0; it < 16; ++it) {
      const int flat = it * 512 + tid;
      const int row = flat >> 7, k0 = (flat & 127) * 8;
      *(bf16x8*)(xs + row * XS_STRIDE + k0) = *(const bf16x8*)(xsrc + row * HID + k0);
    }
    __syncthreads();
    const int g = wv >> 1;
    for (int nt = 0; nt < 32; ++nt) {
      const int col = wv * 512 + nt * 16 + col16;        // global gate col
      const u16* bp = Wt + (size_t)col * KDIM + HID + kg * 8;  // x-half of Wt row
      f32x4 acc[4];
      #pragma unroll
      for (int mt = 0; mt < 4; ++mt) acc[mt] = (f32x4){0.f, 0.f, 0.f, 0.f};
      #pragma unroll 4
      for (int kt = 0; kt < 32; ++kt) {
        const bf16x8 bw = *(const bf16x8*)(bp + kt * 32);
        #pragma unroll
        for (int mt = 0; mt < 4; ++mt) {
          const bf16x8 av = *(const bf16x8*)(xs + (mt * 16 + col16) * XS_STRIDE
                                                + kt * 32 + kg * 8);
          acc[mt] = __builtin_amdgcn_mfma_f32_16x16x32_bf16(av, bw, acc[mt], 0, 0, 0);
        }
      }
      const int bid16 = (wv & 1) * 32 + nt;
      #pragma unroll
      for (int mt = 0; mt < 4; ++mt) {
        u16* dst = gxF + ((((size_t)bid16 * SEQ + t) * 4 + g) * 16 + col16) * 64
                       + mt * 16 + kg * 4;
        const u32 lo = (u32)f2bf(acc[mt][0]) | ((u32)f2bf(acc[mt][1]) << 16);
        const u32 hi = (u32)f2bf(acc[mt][2]) | ((u32)f2bf(acc[mt][3]) << 16);
        *(uint2*)dst = make_uint2(lo, hi);
      }
    }
  }
}

// ---------- sequential LSTM: h-recurrence only + clock-warming fillers ----------
__global__ __launch_bounds__(512) void lstm_seq(
    const float* __restrict__ bias,  // [4096]
    const float* __restrict__ h0,    // [1024]
    const float* __restrict__ c0,    // [1024]
    const u16* __restrict__ Wt,      // [4096][2048] bf16
    const u16* __restrict__ gxF,     // [64][512][4][16][64] bf16
    u16* __restrict__ hbuf,          // [2][64][1024] bf16 (LLC traffic)
    float* __restrict__ out,         // [2][64][1024] f32
    u32* __restrict__ bar)
{
  const int tid = threadIdx.x;
  const int bid = blockIdx.x;

  if (bid >= NBLK) {
    // clock-warming filler; exits when any worker sets DONE_FLAG. Bounded cap.
    float f0 = 1.f + tid * 1e-6f, f1 = 1.1f, f2 = 1.2f, f3 = 1.3f;
    const float a = 1.000001f, b = 1e-7f;
    for (u32 it = 0; it < (1u << 22); ++it) {
      #pragma unroll
      for (int j = 0; j < 64; ++j) {
        f0 = __builtin_fmaf(a, f0, b); f1 = __builtin_fmaf(a, f1, b);
        f2 = __builtin_fmaf(a, f2, b); f3 = __builtin_fmaf(a, f3, b);
      }
      if ((it & 255u) == 0u && llc_load_u32(bar + DONE_FLAG) != 0u) break;
    }
    asm volatile("" :: "v"(f0), "v"(f1), "v"(f2), "v"(f3));
    return;
  }

  __shared__ float gb[64 * GB_STRIDE];

  const int lane = tid & 63;
  const int wave = tid >> 6;
  const int nh = wave & 1;        // gate pair
  const int kq = wave >> 1;       // K quarter
  const int col16 = lane & 15;
  const int kg = lane >> 4;

  // ---- one-time: Wh (h-half of Wt) -> VGPRs ----
  bf16x8 wh[8][2];
  #pragma unroll
  for (int kt = 0; kt < 8; ++kt)
    #pragma unroll
    for (int nt = 0; nt < 2; ++nt) {
      const int g = nh * 2 + nt;
      wh[kt][nt] = *(const bf16x8*)(Wt + (size_t)(g * HID + bid * 16 + col16) * KDIM
                                       + kq * 256 + kt * 32 + kg * 8);
    }
  const float bv0 = bias[(nh * 2 + 0) * HID + bid * 16 + col16];
  const float bv1 = bias[(nh * 2 + 1) * HID + bid * 16 + col16];

  // ---- per-thread output cells (rows r0, r0+32; col colg); c in regs ----
  const int r0 = tid >> 4;
  const int colg = bid * 16 + (tid & 15);
  float cst0 = c0[colg], cst1 = cst0;
  {
    const u16 h0b = f2bf(h0[colg]);
    llc_store_u16(hbuf + (size_t)r0 * HID + colg, h0b);
    llc_store_u16(hbuf + (size_t)(r0 + 32) * HID + colg, h0b);
  }
  __syncthreads();
  if (tid == 0) llc_store_u32(bar + bid, 1u);

  // ---- loop-carried gx prefetch (kq==0 waves only; private, L2-cached) ----
  uint2 gxr[8];
  auto gxload = [&](int t) {
    if (kq == 0) {
      const u16* sb = gxF + ((size_t)bid * SEQ + t) * 4096;
      #pragma unroll
      for (int mt = 0; mt < 4; ++mt)
        #pragma unroll
        for (int nt = 0; nt < 2; ++nt)
          gxr[mt * 2 + nt] = *(const uint2*)(sb + ((nh * 2 + nt) * 16 + col16) * 64
                                                + mt * 16 + kg * 4);
    }
  };
  gxload(0);

  f32x4 acc[4][2];
  const size_t aoff = (size_t)col16 * HID + kq * 256 + kg * 8;

  for (int t = 0; t < SEQ; ++t) {
    const u32 gen = (u32)t + 1;
    // ---- wait for h_t ----
    if (tid < NBLK) {
      for (;;) {
        const u32 fl = llc_load_u32(bar + tid);
        if (fl >= gen) break;
        __builtin_amdgcn_s_sleep(1);
      }
    }
    __syncthreads();

    // ---- h_t @ Wh: pipelined LLC loads + MFMA (acc from zero) ----
    #pragma unroll
    for (int mt = 0; mt < 4; ++mt) {
      acc[mt][0] = (f32x4){0.f, 0.f, 0.f, 0.f};
      acc[mt][1] = (f32x4){0.f, 0.f, 0.f, 0.f};
    }
    const u16* hbase = hbuf + (size_t)(t & 1) * (BATCH * HID) + aoff;
    {
      bf16x8 ha[8], hb2[8];
      asm volatile("s_waitcnt vmcnt(0)" ::: "memory");
      LLC_LOAD8(ha, hbase);
      #pragma unroll
      for (int mt = 0; mt < 4; ++mt) {
        if (mt < 3) {
          const u16* hn = hbase + (size_t)(mt + 1) * 16 * HID;
          if (mt & 1) { LLC_LOAD8(ha, hn); } else { LLC_LOAD8(hb2, hn); }
          asm volatile("s_waitcnt vmcnt(8)" ::: "memory");
        } else {
          asm volatile("s_waitcnt vmcnt(0)" ::: "memory");
        }
        __builtin_amdgcn_sched_barrier(0);
        #pragma unroll
        for (int kt = 0; kt < 8; ++kt) {
          const bf16x8 av = (mt & 1) ? hb2[kt] : ha[kt];
          acc[mt][0] = __builtin_amdgcn_mfma_f32_16x16x32_bf16(av, wh[kt][0], acc[mt][0], 0, 0, 0);
          acc[mt][1] = __builtin_amdgcn_mfma_f32_16x16x32_bf16(av, wh[kt][1], acc[mt][1], 0, 0, 0);
        }
      }
    }

    // ---- K-reduction in LDS; kq0 seeds with bias + gates_x ----
    if (kq == 0) {
      #pragma unroll
      for (int mt = 0; mt < 4; ++mt)
        #pragma unroll
        for (int nt = 0; nt < 2; ++nt) {
          const float bv = nt ? bv1 : bv0;
          const uint2 gv = gxr[mt * 2 + nt];
          const float gx0 = bf2f(gv.x & 0xffffu), gx1 = bf2f(gv.x >> 16);
          const float gx2 = bf2f(gv.y & 0xffffu), gx3 = bf2f(gv.y >> 16);
          float* gp = gb + (mt * 16 + kg * 4) * GB_STRIDE + (nh * 2 + nt) * 16 + col16;
          gp[0 * GB_STRIDE] = acc[mt][nt][0] + bv + gx0;
          gp[1 * GB_STRIDE] = acc[mt][nt][1] + bv + gx1;
          gp[2 * GB_STRIDE] = acc[mt][nt][2] + bv + gx2;
          gp[3 * GB_STRIDE] = acc[mt][nt][3] + bv + gx3;
        }
    }
    __syncthreads();
    if (kq != 0) {
      #pragma unroll
      for (int mt = 0; mt < 4; ++mt)
        #pragma unroll
        for (int nt = 0; nt < 2; ++nt)
          #pragma unroll
          for (int r = 0; r < 4; ++r)
            atomicAdd(&gb[(mt * 16 + kg * 4 + r) * GB_STRIDE + (nh * 2 + nt) * 16 + col16],
                      acc[mt][nt][r]);
    }
    __syncthreads();

    // ---- gates -> nonlinearity -> c,h update (2 cells/thread) ----
    u16* hw = hbuf + (size_t)((t + 1) & 1) * (BATCH * HID);
    const int cl = tid & 15;
    #pragma unroll
    for (int cc = 0; cc < 2; ++cc) {
      const int row = r0 + cc * 32;
      const float vf = gb[row * GB_STRIDE + cl];
      const float vi = gb[row * GB_STRIDE + 16 + cl];
      const float vg = gb[row * GB_STRIDE + 32 + cl];
      const float vo = gb[row * GB_STRIDE + 48 + cl];
      const float ft = 1.f / (1.f + __expf(-vf));
      const float it = 1.f / (1.f + __expf(-vi));
      const float eg = __expf(2.f * vg);
      const float gt = 1.f - 2.f / (eg + 1.f);     // tanh
      const float ot = 1.f / (1.f + __expf(-vo));
      const float cold = cc ? cst1 : cst0;
      const float cn = ft * cold + it * gt;
      const float ec = __expf(2.f * cn);
      const float th = 1.f - 2.f / (ec + 1.f);     // tanh
      const float hn = ot * th;
      if (cc) cst1 = cn; else cst0 = cn;
      llc_store_u16(hw + (size_t)row * HID + colg, f2bf(hn));
      if (t == SEQ - 1) {
        out[(size_t)row * HID + colg] = hn;
        out[(size_t)BATCH * HID + (size_t)row * HID + colg] = cn;
      }
    }
    __syncthreads();   // all waves' write-through h stores acked at LLC

    if (t < SEQ - 1) {
      if (tid == 0) llc_store_u32(bar + bid, gen + 1);  // release first
      gxload(t + 1);                                     // then off-path prefetch
    } else {
      if (tid == 0) llc_store_u32(bar + DONE_FLAG, 1u);  // filler exit
    }
  }
}

// ---------- fallback (== R4's proven kernel) for small workspaces ----------
__global__ __launch_bounds__(512) void lstm_fallback(
    const u16* __restrict__ xb, const float* __restrict__ bias,
    const float* __restrict__ h0, const float* __restrict__ c0,
    const u16* __restrict__ Wt, u16* __restrict__ hbuf,
    float* __restrict__ out, u32* __restrict__ bar)
{
  extern __shared__ char smem[];
  u16* wx = (u16*)smem;
  float* gb = (float*)(smem + WX_BYTES);
  const int tid = threadIdx.x;
  const int lane = tid & 63;
  const int wave = tid >> 6;
  const int nh = wave & 1;
  const int kq = wave >> 1;
  const int col16 = lane & 15;
  const int kg = lane >> 4;
  const int bid = blockIdx.x;

  bf16x8 wh[8][2];
  u16* wxw = wx + (size_t)wave * (16 * 64 * 8) + (size_t)lane * 8;
  #pragma unroll
  for (int kt = 0; kt < 8; ++kt)
    #pragma unroll
    for (int nt = 0; nt < 2; ++nt) {
      const int g = nh * 2 + nt;
      const u16* wrow = Wt + (size_t)(g * HID + bid * 16 + col16) * KDIM
                           + kq * 256 + kt * 32 + kg * 8;
      wh[kt][nt] = *(const bf16x8*)(wrow);
      *(bf16x8*)(wxw + (size_t)(kt * 2 + nt) * (64 * 8)) = *(const bf16x8*)(wrow + HID);
    }
  const float bv0 = bias[(nh * 2 + 0) * HID + bid * 16 + col16];
  const float bv1 = bias[(nh * 2 + 1) * HID + bid * 16 + col16];
  const int r0 = tid >> 4;
  const int colg = bid * 16 + (tid & 15);
  float cst0 = c0[colg], cst1 = cst0;
  {
    const u16 h0b = f2bf(h0[colg]);
    llc_store_u16(hbuf + (size_t)r0 * HID + colg, h0b);
    llc_store_u16(hbuf + (size_t)(r0 + 32) * HID + colg, h0b);
  }
  __syncthreads();
  if (tid == 0) llc_store_u32(bar + bid, 1u);

  f32x4 acc[4][2];
  const size_t aoff = (size_t)col16 * HID + kq * 256 + kg * 8;
  auto xphase = [&](int t) {
    #pragma unroll
    for (int mt = 0; mt < 4; ++mt) {
      acc[mt][0] = (f32x4){0.f, 0.f, 0.f, 0.f};
      acc[mt][1] = (f32x4){0.f, 0.f, 0.f, 0.f};
    }
    const u16* xbase = xb + (size_t)t * (BATCH * HID) + aoff;
    #pragma unroll
    for (int mt = 0; mt < 4; ++mt) {
      bf16x8 a[8];
      #pragma unroll
      for (int kt = 0; kt < 8; ++kt)
        a[kt] = *(const bf16x8*)(xbase + (size_t)mt * 16 * HID + kt * 32);
      #pragma unroll
      for (int kt = 0; kt < 8; ++kt) {
        const bf16x8 w0 = *(const bf16x8*)(wxw + (size_t)(kt * 2 + 0) * (64 * 8));
        const bf16x8 w1 = *(const bf16x8*)(wxw + (size_t)(kt * 2 + 1) * (64 * 8));
        acc[mt][0] = __builtin_amdgcn_mfma_f32_16x16x32_bf16(a[kt], w0, acc[mt][0], 0, 0, 0);
        acc[mt][1] = __builtin_amdgcn_mfma_f32_16x16x32_bf16(a[kt], w1, acc[mt][1], 0, 0, 0);
      }
    }
  };
  xphase(0);
  for (int t = 0; t < SEQ; ++t) {
    const u32 gen = (u32)t + 1;
    if (tid < NBLK) {
      for (;;) {
        const u32 fl = llc_load_u32(bar + tid);
        if (fl >= gen) break;
        __builtin_amdgcn_s_sleep(1);
      }
    }
    __syncthreads();
    const u16* hbase = hbuf + (size_t)(t & 1) * (BATCH * HID) + aoff;
    {
      bf16x8 ha[8], hb2[8];
      asm volatile("s_waitcnt vmcnt(0)" ::: "memory");
      LLC_LOAD8(ha, hbase);
      #pragma unroll
      for (int mt = 0; mt < 4; ++mt) {
        if (mt < 3) {
          const u16* hn = hbase + (size_t)(mt + 1) * 16 * HID;
          if (mt & 1) { LLC_LOAD8(ha, hn); } else { LLC_LOAD8(hb2, hn); }
          asm volatile("s_waitcnt vmcnt(8)" ::: "memory");
        } else {
          asm volatile("s_waitcnt vmcnt(0)" ::: "memory");
        }
        __builtin_amdgcn_sched_barrier(0);
        #pragma unroll
        for (int kt = 0; kt < 8; ++kt) {
          const bf16x8 av = (mt & 1) ? hb2[kt] : ha[kt];
          acc[mt][0] = __builtin_amdgcn_mfma_f32_16x16x32_bf16(av, wh[kt][0], acc[mt][0], 0, 0, 0);
          acc[mt][1] = __builtin_amdgcn_mfma_f32_16x16x32_bf16(av, wh[kt][1], acc[mt][1], 0, 0, 0);
        }
      }
    }
    if (kq == 0) {
      #pragma unroll
      for (int mt = 0; mt < 4; ++mt)
        #pragma unroll
        for (int nt = 0; nt < 2; ++nt) {
          const float bv = nt ? bv1 : bv0;
          #pragma unroll
          for (int r = 0; r < 4; ++r)
            gb[(mt * 16 + kg * 4 + r) * GB_STRIDE + (nh * 2 + nt) * 16 + col16] =
                acc[mt][nt][r] + bv;
        }
    }
    __syncthreads();
    if (kq != 0) {
      #pragma unroll
      for (int mt = 0; mt < 4; ++mt)
        #pragma unroll
        for (int nt = 0; nt < 2; ++nt)
          #pragma unroll
          for (int r = 0; r < 4; ++r)
            atomicAdd(&gb[(mt * 16 + kg * 4 + r) * GB_STRIDE + (nh * 2 + nt) * 16 + col16],
                      acc[mt][nt][r]);
    }
    __syncthreads();
    u16* hw = hbuf + (size_t)((t + 1) & 1) * (BATCH * HID);
    const int cl = tid & 15;
    #pragma unroll
    for (int cc = 0; cc < 2; ++cc) {
      const int row = r0 + cc * 32;
      const float vf = gb[row * GB_STRIDE + cl];
      const float vi = gb[row * GB_STRIDE + 16 + cl];
      const float vg = gb[row * GB_STRIDE + 32 + cl];
      const float vo = gb[row * GB_STRIDE + 48 + cl];
      const float ft = 1.f / (1.f + __expf(-vf));
      const float it = 1.f / (1.f + __expf(-vi));
      const float eg = __expf(2.f * vg);
      const float gt = 1.f - 2.f / (eg + 1.f);
      const float ot = 1.f / (1.f + __expf(-vo));
      const float cold = cc ? cst1 : cst0;
      const float cn = ft * cold + it * gt;
      const float ec = __expf(2.f * cn);
      const float th = 1.f - 2.f / (ec + 1.f);
      const float hn = ot * th;
      if (cc) cst1 = cn; else cst0 = cn;
      llc_store_u16(hw + (size_t)row * HID + colg, f2bf(hn));
      if (t == SEQ - 1) {
        out[(size_t)row * HID + colg] = hn;
        out[(size_t)BATCH * HID + (size_t)row * HID + colg] = cn;
      }
    }
    __syncthreads();
    if (t < SEQ - 1) {
      if (tid == 0) llc_store_u32(bar + bid, gen + 1);
      xphase(t + 1);
    }
  }
}

extern "C" void kernel_launch(void* const* d_in, const int* in_sizes, int n_in,
                              void* d_out, int out_size, void* d_ws, size_t ws_size,
                              hipStream_t stream) {
  const float* x    = (const float*)d_in[0];  // [512][64][1024]
  const float* W    = (const float*)d_in[1];  // [2048][4096]
  const float* bias = (const float*)d_in[2];  // [4096]
  const float* h0   = (const float*)d_in[3];  // [1024]
  const float* c0   = (const float*)d_in[4];  // [1024]
  float* out = (float*)d_out;                 // [2][64][1024]

  char* w = (char*)d_ws;
  u16* Wt   = (u16*)w;                                   // 16 MB
  u16* xbq  = (u16*)(w + ((size_t)16 << 20));            // 64 MB
  u16* hbuf = (u16*)(w + ((size_t)80 << 20));            // 256 KB (512K region)
  u32* bar  = (u32*)(w + ((size_t)80 << 20) + (512 << 10));
  u16* gxF  = (u16*)(w + ((size_t)81 << 20));            // 256 MB
  const size_t need_small = ((size_t)80 << 20) + (512 << 10) + 4096;
  const size_t need_big   = ((size_t)81 << 20) + ((size_t)256 << 20);
  if (ws_size < need_small) return;

  (void)hipFuncSetAttribute((const void*)prepass_gx,
                            hipFuncAttributeMaxDynamicSharedMemorySize, SMEM_PP);
  (void)hipFuncSetAttribute((const void*)lstm_fallback,
                            hipFuncAttributeMaxDynamicSharedMemorySize, SMEM_FB);

  hipLaunchKernelGGL(prep_w, dim3(32, 64), dim3(256), 0, stream, W, Wt, bar);
  hipLaunchKernelGGL(prep_x, dim3(4096), dim3(256), 0, stream, x, xbq);
  if (ws_size >= need_big) {
    hipLaunchKernelGGL(prepass_gx, dim3(256), dim3(512), SMEM_PP, stream, xbq, Wt, gxF);
    hipLaunchKernelGGL(lstm_seq, dim3(NBLK_TOTAL), dim3(512), 0, stream,
                       bias, h0, c0, Wt, gxF, hbuf, out, bar);
  } else {
    hipLaunchKernelGGL(lstm_fallback, dim3(NBLK), dim3(512), SMEM_FB, stream,
                       xbq, bias, h0, c0, Wt, hbuf, out, bar);
  }
}